// Round 2
// baseline (69.783 us; speedup 1.0000x reference)
//
#include <hip/hip_runtime.h>

// PolynomialRegression via bf16 MFMA, SINGLE launch (R8: gbuild fused away).
//   y[b][o] = bias_o + sum_i x[b][i] * ( (U_o x[b])_i + W1[o][i] )
// R8 change vs R7 (69.2 us, 2-launch best): B-operand fragments are packed
//   fp32->bf16 on the fly from W's packed-triangular layout (identical pack2
//   rounding as gbuild -> numerics unchanged). Diagonal 32x32 chunks (t==0 or
//   t==rem, wave-uniform) get per-lane AND masks; mask pattern is group-
//   independent (b0 rows: col<ln, b1 rows: col<16+ln). Removes the gbuild
//   launch, the inter-kernel dependency bubble, and all workspace use.
// R9: identical resubmit — R8 bench died to container-acquire infra failure,
//   no signal received. OOB audit clean (max W idx 331529 < 331530).
// Theory: kernel is >30x off MFMA/HBM/L2 rooflines; time is launch/latency
//   dominated. Predict dur 69 -> ~60; absmax identical (0.03125).

#define DD 256
#define NF 33153
#define TPB 256
#define ASTRIDE 264   // bf16 elems; 528 B row stride -> 2-way LDS alias (free)

typedef __attribute__((ext_vector_type(8))) short short8;
typedef __attribute__((ext_vector_type(4))) float floatx4;
typedef __attribute__((ext_vector_type(4), aligned(4))) float float4a;

union S8U { unsigned u[4]; short8 s; };

__device__ inline unsigned pack2(float lo, float hi) {   // 2xfp32 -> bf16x2, half-up
    unsigned a = __builtin_bit_cast(unsigned, hi) + 0x8000u;
    unsigned b = __builtin_bit_cast(unsigned, lo) + 0x8000u;
    return __builtin_amdgcn_perm(a, b, 0x07060302u);
}

// 8 consecutive fp32 -> short8 of bf16 (dword-aligned source is sufficient;
// same float4a aligned(4) loads the old gbuild kernel used).
__device__ inline short8 load_pack8(const float* __restrict__ p) {
    float4a v0 = *(const float4a*)p;
    float4a v1 = *(const float4a*)(p + 4);
    S8U r;
    r.u[0] = pack2(v0.x, v0.y); r.u[1] = pack2(v0.z, v0.w);
    r.u[2] = pack2(v1.x, v1.y); r.u[3] = pack2(v1.z, v1.w);
    return r.s;
}

// Packed upper-triangular: element (i,j), j>=i, lives at W[o*NF + troff(i) + j].
// For j<i this reads in-bounds garbage from earlier rows (masked to zero).
__device__ inline int troff(int i) { return 257 + 255 * i - ((i * (i - 1)) >> 1); }

__global__ __launch_bounds__(TPB, 3)
void PolynomialRegression_75385265979710_kernel(const float* __restrict__ x,
                                                const float* __restrict__ W,
                                                float* __restrict__ out) {
    __shared__ __align__(16) unsigned short As[64 * ASTRIDE];  // 33792 B
    __shared__ float red[4 * 64];

    const int tid  = threadIdx.x;
    const int lane = tid & 63, wave = tid >> 6;
    const int ln   = lane & 15, quad = lane >> 4;
    const int q8   = quad * 8;
    const int rowbase = blockIdx.x * 64;
    const int o  = blockIdx.y;
    const int g1 = wave, g2 = 7 - wave;
    const int rem = 8 - wave;            // chunks in group g1

    // --- stage x-tile (64 x 256) fp32 -> bf16 into padded LDS ---
#pragma unroll
    for (int it = 0; it < 8; ++it) {
        int idx = it * 2048 + tid * 8;
        int r = idx >> 8, c = idx & 255;
        const float* src = &x[(rowbase + r) * DD + c];
        float4a v0 = *(const float4a*)src;
        float4a v1 = *(const float4a*)(src + 4);
        S8U p;
        p.u[0] = pack2(v0.x, v0.y); p.u[1] = pack2(v0.z, v0.w);
        p.u[2] = pack2(v1.x, v1.y); p.u[3] = pack2(v1.z, v1.w);
        *(short8*)&As[r * ASTRIDE + c] = p.s;
    }

    const float* __restrict__ Wo = W + o * NF;

    // per-lane W offsets for this wave's 4 B-rows (abs column gets added later)
    const int offA0 = troff(g1 * 32 + ln)      + q8;
    const int offA1 = troff(g1 * 32 + 16 + ln) + q8;
    const int offB0 = troff(g2 * 32 + ln)      + q8;
    const int offB1 = troff(g2 * 32 + 16 + ln) + q8;

    // diagonal-chunk zero masks (col-in-tile = q8+e; b0 row-in-tile = ln,
    // b1 row-in-tile = 16+ln; zero where col < row). Group-independent.
    unsigned mA[4], mB[4];
#pragma unroll
    for (int w2 = 0; w2 < 4; ++w2) {
        mA[w2] = ((q8 + 2 * w2     < ln) ? 0u : 0x0000FFFFu)
               | ((q8 + 2 * w2 + 1 < ln) ? 0u : 0xFFFF0000u);
        mB[w2] = ((q8 + 2 * w2     < 16 + ln) ? 0u : 0x0000FFFFu)
               | ((q8 + 2 * w2 + 1 < 16 + ln) ? 0u : 0xFFFF0000u);
    }

    // hoisted epilogue constants (latency hides under K-loop)
    int iRow[4];
    float w1v[4];
#pragma unroll
    for (int nt = 0; nt < 4; ++nt) {
        int g = (nt < 2) ? g1 : g2;
        iRow[nt] = g * 32 + (nt & 1) * 16 + ln;
        w1v[nt]  = Wo[1 + iRow[nt]];
    }
    const float bias = Wo[0];

    // prefetch chunk t=0 (kc=g1, diagonal) B-frags: overlaps staging+barrier
    S8U pb0, pb1;
    pb0.s = load_pack8(Wo + offA0 + g1 * 32);
    pb1.s = load_pack8(Wo + offA1 + g1 * 32);

    __syncthreads();

    floatx4 acc[4][4];   // [m_tile][n_tile: 0,1 = group g1; 2,3 = group g2]
#pragma unroll
    for (int mt = 0; mt < 4; ++mt)
#pragma unroll
        for (int nt = 0; nt < 4; ++nt) acc[mt][nt] = (floatx4)0.f;

    // --- uniform 9-chunk loop, fully unrolled: t<rem -> (g1, kc=g1+t),
    //     else -> (g2, kc=g2+(t-rem)). B-frags packed on the fly from W.
#pragma unroll
    for (int t = 0; t < 9; ++t) {
        const bool first = (t < rem);                      // wave-uniform
        const int kc = first ? (g1 + t) : (g2 + (t - rem));
        const int co = kc * 32;
        S8U b0, b1;
        if (t == 0) {            // preloaded before the barrier
            b0 = pb0; b1 = pb1;
        } else {
            b0.s = load_pack8(Wo + (first ? offA0 : offB0) + co);
            b1.s = load_pack8(Wo + (first ? offA1 : offB1) + co);
        }
        if (t == 0 || t == rem) {                          // diagonal chunk
#pragma unroll
            for (int w2 = 0; w2 < 4; ++w2) { b0.u[w2] &= mA[w2]; b1.u[w2] &= mB[w2]; }
        }
        short8 a[4];
#pragma unroll
        for (int mt = 0; mt < 4; ++mt)
            a[mt] = *(const short8*)&As[(mt * 16 + ln) * ASTRIDE + co + q8];
        if (first) {
#pragma unroll
            for (int mt = 0; mt < 4; ++mt) {
                acc[mt][0] = __builtin_amdgcn_mfma_f32_16x16x32_bf16(a[mt], b0.s, acc[mt][0], 0, 0, 0);
                acc[mt][1] = __builtin_amdgcn_mfma_f32_16x16x32_bf16(a[mt], b1.s, acc[mt][1], 0, 0, 0);
            }
        } else {
#pragma unroll
            for (int mt = 0; mt < 4; ++mt) {
                acc[mt][2] = __builtin_amdgcn_mfma_f32_16x16x32_bf16(a[mt], b0.s, acc[mt][2], 0, 0, 0);
                acc[mt][3] = __builtin_amdgcn_mfma_f32_16x16x32_bf16(a[mt], b1.s, acc[mt][3], 0, 0, 0);
            }
        }
    }

    // --- epilogue: y_part[m] = sum_{i in wave's set} x[m][i]*(T[m][i]+W1[o][i])
#pragma unroll
    for (int mt = 0; mt < 4; ++mt) {
#pragma unroll
        for (int r = 0; r < 4; ++r) {
            const int m = mt * 16 + quad * 4 + r;   // C/D: row=quad*4+reg, col=ln
            float p = 0.f;
#pragma unroll
            for (int nt = 0; nt < 4; ++nt) {
                unsigned u = As[m * ASTRIDE + iRow[nt]];
                float xv = __builtin_bit_cast(float, u << 16);
                p = fmaf(xv, acc[mt][nt][r] + w1v[nt], p);
            }
            p += __shfl_xor(p, 1);
            p += __shfl_xor(p, 2);
            p += __shfl_xor(p, 4);
            p += __shfl_xor(p, 8);
            if (ln == 0) red[wave * 64 + m] = p;
        }
    }
    __syncthreads();

    if (tid < 64) {
        float s = red[tid] + red[64 + tid] + red[128 + tid] + red[192 + tid]
                + bias;
        out[(rowbase + tid) * 10 + o] = s;
    }
}

extern "C" void kernel_launch(void* const* d_in, const int* in_sizes, int n_in,
                              void* d_out, int out_size, void* d_ws, size_t ws_size,
                              hipStream_t stream) {
    const float* x = (const float*)d_in[0];   // (4096, 256)
    const float* W = (const float*)d_in[1];   // (10, 33153)
    float* out = (float*)d_out;               // (4096, 10)

    dim3 grid(4096 / 64, 10);
    PolynomialRegression_75385265979710_kernel<<<grid, TPB, 0, stream>>>(x, W, out);
}